// Round 5
// baseline (345.681 us; speedup 1.0000x reference)
//
#include <hip/hip_runtime.h>
#include <math.h>

// MultiHeadAttentionMemory: B=256, F=4096, M=4096 memories.
// seq_len==1 => attention==identity => o = (z@Wv+bv)@Wo+bo  (Wq/Wk dead).
// Split-bf16 (bf16x3: ah*bh + ah*bl + al*bh) MFMA for the 3 precision-
// sensitive GEMMs; plain bf16 MFMA for z_hat = w@mem.
// GEMM: depth-3 counted-vmcnt pipeline (T3/T4), raw s_barrier, setprio (T5).
// B staged via global_load_lds into 3 LDS buffers; A register-prefetched.
#define MB 256
#define FF 4096

typedef __attribute__((ext_vector_type(8))) short short8v;
typedef __attribute__((ext_vector_type(4))) short short4v;
typedef __attribute__((ext_vector_type(16))) float f32x16;

__device__ __forceinline__ unsigned short bf16_rne(float f) {
    unsigned u = __builtin_bit_cast(unsigned, f);
    u += 0x7fffu + ((u >> 16) & 1u);
    return (unsigned short)(u >> 16);
}
__device__ __forceinline__ float bf16_f(unsigned short h) {
    unsigned u = ((unsigned)h) << 16;
    return __builtin_bit_cast(float, u);
}

// async global->LDS, 16B per lane; lds ptr must be wave-uniform.
#define GLL16(g, l)                                                          \
    __builtin_amdgcn_global_load_lds(                                        \
        (const __attribute__((address_space(1))) unsigned int*)(g),          \
        (__attribute__((address_space(3))) unsigned int*)(l), 16, 0, 0)

// ---------------- reductions ----------------
__device__ __forceinline__ float block_reduce_sum(float v, float* red) {
    const int tid = threadIdx.x;
    red[tid] = v; __syncthreads();
    for (int s = 128; s > 0; s >>= 1) {
        if (tid < s) red[tid] += red[tid + s];
        __syncthreads();
    }
    float r = red[0]; __syncthreads();
    return r;
}
__device__ __forceinline__ float block_reduce_max(float v, float* red) {
    const int tid = threadIdx.x;
    red[tid] = v; __syncthreads();
    for (int s = 128; s > 0; s >>= 1) {
        if (tid < s) red[tid] = fmaxf(red[tid], red[tid + s]);
        __syncthreads();
    }
    float r = red[0]; __syncthreads();
    return r;
}

// dst[row] = max(||src[row,:]||, 1e-8)
__global__ __launch_bounds__(256) void rownorm_kernel(
    const float* __restrict__ src, float* __restrict__ dst, int ncols)
{
    __shared__ float red[256];
    const int row = blockIdx.x, tid = threadIdx.x;
    const float4* p = (const float4*)(src + (size_t)row * ncols);
    float s = 0.f;
    for (int i = tid; i < ncols / 4; i += 256) {
        float4 v = p[i];
        s += v.x * v.x + v.y * v.y + v.z * v.z + v.w * v.w;
    }
    float tot = block_reduce_sum(s, red);
    if (tid == 0) dst[row] = fmaxf(sqrtf(tot), 1e-8f);
}

// ---------------- fp32 -> bf16 hi/lo split (straight) ----------------
__global__ __launch_bounds__(256) void split_plain(
    const float* __restrict__ src, unsigned short* __restrict__ hi,
    unsigned short* __restrict__ lo)
{
    const size_t i4 = (size_t)blockIdx.x * 256 + threadIdx.x;
    const float4 v = *(const float4*)(src + i4 * 4);
    unsigned short h0 = bf16_rne(v.x), h1 = bf16_rne(v.y), h2 = bf16_rne(v.z), h3 = bf16_rne(v.w);
    short4v hv = { (short)h0, (short)h1, (short)h2, (short)h3 };
    *(short4v*)(hi + i4 * 4) = hv;
    short4v lv = { (short)bf16_rne(v.x - bf16_f(h0)), (short)bf16_rne(v.y - bf16_f(h1)),
                   (short)bf16_rne(v.z - bf16_f(h2)), (short)bf16_rne(v.w - bf16_f(h3)) };
    *(short4v*)(lo + i4 * 4) = lv;
}

// ---------------- mem: fused split + rownorm (one 64MB pass) ----------------
__global__ __launch_bounds__(256) void split_norm_mem(
    const float* __restrict__ src, unsigned short* __restrict__ hi,
    unsigned short* __restrict__ lo, float* __restrict__ nrm)
{
    __shared__ float red[256];
    const int row = blockIdx.x, tid = threadIdx.x;
    const float4* p = (const float4*)(src + (size_t)row * FF);
    float s = 0.f;
    for (int i = tid; i < FF / 4; i += 256) {
        float4 v = p[i];
        s += v.x * v.x + v.y * v.y + v.z * v.z + v.w * v.w;
        unsigned short h0 = bf16_rne(v.x), h1 = bf16_rne(v.y), h2 = bf16_rne(v.z), h3 = bf16_rne(v.w);
        const size_t ob = (size_t)row * FF + i * 4;
        short4v hv = { (short)h0, (short)h1, (short)h2, (short)h3 };
        *(short4v*)(hi + ob) = hv;
        short4v lv = { (short)bf16_rne(v.x - bf16_f(h0)), (short)bf16_rne(v.y - bf16_f(h1)),
                       (short)bf16_rne(v.z - bf16_f(h2)), (short)bf16_rne(v.w - bf16_f(h3)) };
        *(short4v*)(lo + ob) = lv;
    }
    float tot = block_reduce_sum(s, red);
    if (tid == 0) nrm[row] = fmaxf(sqrtf(tot), 1e-8f);
}

// ---------------- transpose + split: src[4096][4096] f32 -> dstT[n][k] bf16 ----------------
template <int WRITE_LO>
__global__ __launch_bounds__(256) void transpose_split(
    const float* __restrict__ src, unsigned short* __restrict__ hi,
    unsigned short* __restrict__ lo)
{
    __shared__ float tile[32][33];
    const int bj = blockIdx.x;  // col block of src (= out row block)
    const int bi = blockIdx.y;  // row block of src (= out col block)
    const int t = threadIdx.x;
    const int ty = t >> 3, tx4 = (t & 7) << 2;
    const float4 v = *(const float4*)(src + (size_t)(bi * 32 + ty) * FF + bj * 32 + tx4);
    tile[ty][tx4 + 0] = v.x; tile[ty][tx4 + 1] = v.y;
    tile[ty][tx4 + 2] = v.z; tile[ty][tx4 + 3] = v.w;
    __syncthreads();
    float o0 = tile[tx4 + 0][ty], o1 = tile[tx4 + 1][ty];
    float o2 = tile[tx4 + 2][ty], o3 = tile[tx4 + 3][ty];
    unsigned short h0 = bf16_rne(o0), h1 = bf16_rne(o1), h2 = bf16_rne(o2), h3 = bf16_rne(o3);
    const size_t ob = (size_t)(bj * 32 + ty) * FF + bi * 32 + tx4;
    short4v hv = { (short)h0, (short)h1, (short)h2, (short)h3 };
    *(short4v*)(hi + ob) = hv;
    if constexpr (WRITE_LO) {
        short4v lv = { (short)bf16_rne(o0 - bf16_f(h0)), (short)bf16_rne(o1 - bf16_f(h1)),
                       (short)bf16_rne(o2 - bf16_f(h2)), (short)bf16_rne(o3 - bf16_f(h3)) };
        *(short4v*)(lo + ob) = lv;
    }
}

// ---------------- MFMA GEMM, split-K, depth-3 counted-vmcnt pipeline ----------------
// C[256][4096] = A[256][4096] @ BT^T  (BT stored [n][k] bf16 planes).
// grid (32, 2, 8); block 256 = 4 waves (2m x 2n), block tile 128x128,
// wave tile 64x64 (2x2 subtiles of 32), BK=32, K-chunk 512 (16 tiles).
// B hi/lo staged via global_load_lds into 3 LDS buffers; tile t+3 staged at
// the end of phase t; raw s_barrier + hand-counted s_waitcnt vmcnt(N)
// (per-wave issue counts; split: STAGE=4 gll + LOADA=8 loads per phase).
// A hi/lo register-direct, 1 tile ahead (compiler-tracked waits).
template <int SPLIT>
__global__ __launch_bounds__(256, 2) void gemm_sk(
    const unsigned short* __restrict__ Ah, const unsigned short* __restrict__ Al,
    const unsigned short* __restrict__ Bh, const unsigned short* __restrict__ Bl,
    float* __restrict__ part)
{
    constexpr int PLANES = SPLIT ? 2 : 1;
    constexpr int BUFBYTES = PLANES * 8192;           // bytes per LDS buffer
    __shared__ unsigned short Bs[3 * PLANES * 4096];  // 3 buffers

    const int tid = threadIdx.x;
    const int lane = tid & 63, w = tid >> 6;
    const int wr = w >> 1, wc = w & 1;
    const int m0 = blockIdx.y * 128 + wr * 64;
    const int bn0 = blockIdx.x * 128;
    const int k0 = blockIdx.z * 512;
    const int l31 = lane & 31;

    // ---- staging addresses (B): slot tid -> n = tid&127, k8 = tid>>7 (+2 on 2nd gll)
    const size_t brow_off = (size_t)(bn0 + (tid & 127)) * FF + k0 + (tid >> 7) * 8;
    const unsigned short* bsh = Bh + brow_off;
    const unsigned short* bsl = SPLIT ? (Bl + brow_off) : bsh;
    char* const lwave = (char*)Bs + (tid >> 6) * 1024;  // wave-uniform base

#define STAGE(BUF_, T_)                                                       \
    {                                                                         \
        GLL16(bsh + (T_) * 32,      lwave + (BUF_) * BUFBYTES + 0);           \
        GLL16(bsh + (T_) * 32 + 16, lwave + (BUF_) * BUFBYTES + 4096);        \
        if constexpr (SPLIT) {                                                \
            GLL16(bsl + (T_) * 32,      lwave + (BUF_) * BUFBYTES + 8192);    \
            GLL16(bsl + (T_) * 32 + 16, lwave + (BUF_) * BUFBYTES + 12288);   \
        }                                                                     \
    }

    // ---- B fragment reads: byte = (k8*128 + n)*16, k8 = KS*2+(lane>>5),
    //      n = wc*64 + NS*32 + l31  -> contiguous 512B runs per wave, conflict-free.
    const char* const fragbase =
        (const char*)Bs + (((lane >> 5) * 128) + wc * 64 + l31) * 16;
#define BFRAG(BUF_, P_, KS_, NS_)                                             \
    (*(const short8v*)(fragbase + (BUF_) * BUFBYTES + (P_) * 8192 + (KS_) * 4096 + (NS_) * 512))

    // ---- A pointers (register-direct)
    const size_t arow = (size_t)(m0 + l31) * FF + k0 + (lane >> 5) * 8;
    const unsigned short* a0h = Ah + arow;
    const unsigned short* a1h = a0h + (size_t)32 * FF;
    const unsigned short* a0l = SPLIT ? (Al + arow) : a0h;
    const unsigned short* a1l = a0l + (size_t)32 * FF;

    short8v cA_0h0, cA_0h1, cA_1h0, cA_1h1, cA_0l0, cA_0l1, cA_1l0, cA_1l1;
    short8v nA_0h0, nA_0h1, nA_1h0, nA_1h1, nA_0l0, nA_0l1, nA_1l0, nA_1l1;

#define LOADA(SET, T_)                                                        \
    {                                                                         \
        const int o_ = (T_) * 32;                                             \
        SET##_0h0 = *(const short8v*)(a0h + o_);                              \
        SET##_0h1 = *(const short8v*)(a0h + o_ + 16);                         \
        SET##_1h0 = *(const short8v*)(a1h + o_);                              \
        SET##_1h1 = *(const short8v*)(a1h + o_ + 16);                         \
        if constexpr (SPLIT) {                                                \
            SET##_0l0 = *(const short8v*)(a0l + o_);                          \
            SET##_0l1 = *(const short8v*)(a0l + o_ + 16);                     \
            SET##_1l0 = *(const short8v*)(a1l + o_);                          \
            SET##_1l1 = *(const short8v*)(a1l + o_ + 16);                     \
        }                                                                     \
    }

    f32x16 acc00 = 0.0f, acc01 = 0.0f, acc10 = 0.0f, acc11 = 0.0f;

#define MFMA(A_, B_, C_) C_ = __builtin_amdgcn_mfma_f32_32x32x16_bf16(A_, B_, C_, 0, 0, 0)
#define MMKS(SET, BUF_, KS_)                                                  \
    {                                                                         \
        short8v bh0 = BFRAG(BUF_, 0, KS_, 0);                                 \
        short8v bh1 = BFRAG(BUF_, 0, KS_, 1);                                 \
        MFMA(SET##_0h##KS_, bh0, acc00); MFMA(SET##_0h##KS_, bh1, acc01);     \
        MFMA(SET##_1h##KS_, bh0, acc10); MFMA(SET##_1h##KS_, bh1, acc11);     \
        if constexpr (SPLIT) {                                                \
            short8v bl0 = BFRAG(BUF_, 1, KS_, 0);                             \
            short8v bl1 = BFRAG(BUF_, 1, KS_, 1);                             \
            MFMA(SET##_0h##KS_, bl0, acc00); MFMA(SET##_0h##KS_, bl1, acc01); \
            MFMA(SET##_1h##KS_, bl0, acc10); MFMA(SET##_1h##KS_, bl1, acc11); \
            MFMA(SET##_0l##KS_, bh0, acc00); MFMA(SET##_0l##KS_, bh1, acc01); \
            MFMA(SET##_1l##KS_, bh0, acc10); MFMA(SET##_1l##KS_, bh1, acc11); \
        }                                                                     \
    }

    // One pipeline phase. WN_ = literal vmcnt immediate guaranteeing the
    // staging loads of tile T_ have landed (counts derived from per-wave
    // issue order; see table below). Never 0 in steady state.
#define PH(T_, WN_, CURS, NXTS)                                               \
    {                                                                         \
        asm volatile("s_waitcnt vmcnt(" #WN_ ")" ::: "memory");               \
        __builtin_amdgcn_s_barrier();                                         \
        asm volatile("" ::: "memory");                                        \
        if ((T_) + 1 < 16) { LOADA(NXTS, (T_) + 1) }                          \
        __builtin_amdgcn_s_setprio(1);                                        \
        MMKS(CURS, (T_) % 3, 0)                                               \
        MMKS(CURS, (T_) % 3, 1)                                               \
        __builtin_amdgcn_s_setprio(0);                                        \
        asm volatile("" ::: "memory");                                        \
        __builtin_amdgcn_s_barrier();                                         \
        asm volatile("" ::: "memory");                                        \
        if ((T_) + 3 < 16) { STAGE((T_) % 3, (T_) + 3) }                      \
    }

    // prologue: stage tiles 0..2 into bufs 0..2, prefetch A(0)
    STAGE(0, 0)
    STAGE(1, 1)
    STAGE(2, 2)
    LOADA(cA, 0)

    // Per-wave vmcnt issue counts (ops younger than stage(T) at wait point):
    //   SPLIT=1: per phase LOADA=8 + STAGE=4 -> steady 24;
    //            t0=16 t1=24 t2=32 t3..13=24 t14=20 t15=16
    //   SPLIT=0: per phase LOADA=4 + STAGE=2 -> steady 12;
    //            t0=8 t1=12 t2=16 t3..13=12 t14=10 t15=8
    if constexpr (SPLIT) {
        PH(0, 16, cA, nA)  PH(1, 24, nA, cA)  PH(2, 32, cA, nA)
        PH(3, 24, nA, cA)  PH(4, 24, cA, nA)  PH(5, 24, nA, cA)
        PH(6, 24, cA, nA)  PH(7, 24, nA, cA)  PH(8, 24, cA, nA)
        PH(9, 24, nA, cA)  PH(10, 24, cA, nA) PH(11, 24, nA, cA)
        PH(12, 24, cA, nA) PH(13, 24, nA, cA) PH(14, 20, cA, nA)
        PH(15, 16, nA, cA)
    } else {
        PH(0, 8, cA, nA)   PH(1, 12, nA, cA)  PH(2, 16, cA, nA)
        PH(3, 12, nA, cA)  PH(4, 12, cA, nA)  PH(5, 12, nA, cA)
        PH(6, 12, cA, nA)  PH(7, 12, nA, cA)  PH(8, 12, cA, nA)
        PH(9, 12, nA, cA)  PH(10, 12, cA, nA) PH(11, 12, nA, cA)
        PH(12, 12, cA, nA) PH(13, 12, nA, cA) PH(14, 10, cA, nA)
        PH(15, 8, nA, cA)
    }
#undef STAGE
#undef BFRAG
#undef LOADA
#undef MFMA
#undef MMKS
#undef PH

    float* pp = part + (size_t)blockIdx.z * (MB * FF);
    const int rbase = m0 + 4 * (lane >> 5);
    const int c0 = bn0 + wc * 64 + l31;
#pragma unroll
    for (int r = 0; r < 16; ++r) {
        const int row0 = rbase + (r & 3) + 8 * (r >> 2);
        float* rp0 = pp + (size_t)row0 * FF + c0;
        rp0[0]  = acc00[r];
        rp0[32] = acc01[r];
        float* rp1 = rp0 + (size_t)32 * FF;
        rp1[0]  = acc10[r];
        rp1[32] = acc11[r];
    }
}

// ---------------- split-K reduce + epilogue ----------------
// MODE 0: +bias -> hi/lo planes.  MODE 1: +bias -> hi/lo + f32.
// MODE 2: /(zn*mn) -> f32.        MODE 3: plain -> f32.
template <int MODE>
__global__ __launch_bounds__(256) void reduce_k(
    const float* __restrict__ part, const float* __restrict__ bias,
    const float* __restrict__ zn, const float* __restrict__ mn,
    unsigned short* __restrict__ hi, unsigned short* __restrict__ lo,
    float* __restrict__ fout)
{
    const size_t idx4 = (size_t)blockIdx.x * 256 + threadIdx.x;
    const size_t base = idx4 * 4;
    float s0 = 0.f, s1 = 0.f, s2 = 0.f, s3 = 0.f;
#pragma unroll
    for (int c = 0; c < 8; ++c) {
        const float4 p = *(const float4*)(part + (size_t)c * (MB * FF) + base);
        s0 += p.x; s1 += p.y; s2 += p.z; s3 += p.w;
    }
    const int col = (int)(base & 4095);
    const int row = (int)(base >> 12);
    if constexpr (MODE == 0 || MODE == 1) {
        s0 += bias[col]; s1 += bias[col + 1]; s2 += bias[col + 2]; s3 += bias[col + 3];
        unsigned short h0 = bf16_rne(s0), h1 = bf16_rne(s1), h2 = bf16_rne(s2), h3 = bf16_rne(s3);
        short4v hv = { (short)h0, (short)h1, (short)h2, (short)h3 };
        *(short4v*)(hi + base) = hv;
        short4v lv = { (short)bf16_rne(s0 - bf16_f(h0)), (short)bf16_rne(s1 - bf16_f(h1)),
                       (short)bf16_rne(s2 - bf16_f(h2)), (short)bf16_rne(s3 - bf16_f(h3)) };
        *(short4v*)(lo + base) = lv;
        if constexpr (MODE == 1) {
            float4 o = { s0, s1, s2, s3 };
            *(float4*)(fout + base) = o;
        }
    } else if constexpr (MODE == 2) {
        const float zr = zn[row];
        float4 o = { s0 / (zr * mn[col]), s1 / (zr * mn[col + 1]),
                     s2 / (zr * mn[col + 2]), s3 / (zr * mn[col + 3]) };
        *(float4*)(fout + base) = o;
    } else {
        float4 o = { s0, s1, s2, s3 };
        *(float4*)(fout + base) = o;
    }
}

// ---------------- softmax + shrinkage + renorm + entropy ----------------
__global__ __launch_bounds__(256) void softmax_shrink_kernel(
    const float* __restrict__ logits, unsigned short* __restrict__ w_hi,
    float* __restrict__ rowent)
{
    constexpr float THRESH = 1.0f / 4096.0f;
    constexpr float EPS = 1e-12f;
    __shared__ float srow[4096];
    __shared__ float red[256];
    const int row = blockIdx.x, tid = threadIdx.x;
    const float4* p = (const float4*)(logits + (size_t)row * FF);
    for (int i = tid; i < FF / 4; i += 256) ((float4*)srow)[i] = p[i];
    __syncthreads();

    float m = -INFINITY;
    for (int i = tid; i < FF; i += 256) m = fmaxf(m, srow[i]);
    m = block_reduce_max(m, red);

    float s = 0.f;
    for (int i = tid; i < FF; i += 256) {
        float e = expf(srow[i] - m);
        srow[i] = e; s += e;
    }
    s = block_reduce_sum(s, red);
    const float inv = 1.0f / s;

    float s2 = 0.f;
    for (int i = tid; i < FF; i += 256) {
        float w = srow[i] * inv;
        float d = w - THRESH;
        float w2 = fmaxf(d, 0.f) * w / (fabsf(d) + EPS);
        srow[i] = w2; s2 += w2;
    }
    __syncthreads();
    s2 = block_reduce_sum(s2, red);
    const float inv2 = 1.0f / fmaxf(s2, EPS);

    float ent = 0.f;
    for (int i = tid; i < FF; i += 256) {
        float w3 = srow[i] * inv2;
        w_hi[(size_t)row * FF + i] = bf16_rne(w3);
        ent -= w3 * logf(w3 + EPS);
    }
    ent = block_reduce_sum(ent, red);
    if (tid == 0) rowent[row] = ent;
}

__global__ __launch_bounds__(256) void loss_kernel(
    const float* __restrict__ rowent, float* __restrict__ out)
{
    __shared__ float red[256];
    const int tid = threadIdx.x;
    float tot = block_reduce_sum(rowent[tid], red);
    if (tid == 0) out[0] = (tot / 256.0f) * 0.0002f;
}

extern "C" void kernel_launch(void* const* d_in, const int* in_sizes, int n_in,
                              void* d_out, int out_size, void* d_ws, size_t ws_size,
                              hipStream_t stream)
{
    // inputs: x, memory, Wq, bq, Wk, bk, Wv, bv, Wo, bo
    const float* x   = (const float*)d_in[0];
    const float* mem = (const float*)d_in[1];
    const float* Wv  = (const float*)d_in[6];
    const float* bv  = (const float*)d_in[7];
    const float* Wo  = (const float*)d_in[8];
    const float* bo  = (const float*)d_in[9];
    float* out = (float*)d_out;

    char* ws = (char*)d_ws;
    unsigned short* T_hi  = (unsigned short*)(ws);                 // 32 MB  (transposed weight hi)
    unsigned short* T_lo  = (unsigned short*)(ws + 33554432ull);   // 32 MB
    unsigned short* M_hi  = (unsigned short*)(ws + 67108864ull);   // 32 MB  (mem split, native)
    unsigned short* M_lo  = (unsigned short*)(ws + 100663296ull);  // 32 MB
    float*          part  = (float*)(ws + 134217728ull);           // 32 MB  (8 split-K partials)
    unsigned short* x_hi  = (unsigned short*)(ws + 167772160ull);  // 2 MB
    unsigned short* x_lo  = (unsigned short*)(ws + 169869312ull);
    unsigned short* v_hi  = (unsigned short*)(ws + 171966464ull);
    unsigned short* v_lo  = (unsigned short*)(ws + 174063616ull);
    unsigned short* o_hi  = (unsigned short*)(ws + 176160768ull);
    unsigned short* o_lo  = (unsigned short*)(ws + 178257920ull);
    float*          o_f32 = (float*)(ws + 180355072ull);           // 4 MB
    float*          logit = (float*)(ws + 184549376ull);           // 4 MB
    unsigned short* w_hi  = (unsigned short*)(ws + 188743680ull);  // 2 MB
    float*          zn    = (float*)(ws + 190840832ull);
    float*          mn    = zn + MB;
    float*          rowe  = mn + FF;

    const dim3 blk(256);
    const dim3 gG(32, 2, 8);      // gemm: N/128, M/128, split-K 8
    const dim3 gT(128, 128);      // transpose tiles
    const int gR = (MB * FF) / (4 * 256);  // 1024

    // prep
    split_plain<<<gR, blk, 0, stream>>>(x, x_hi, x_lo);
    split_norm_mem<<<FF, blk, 0, stream>>>(mem, M_hi, M_lo, mn);

    // v = z @ Wv + bv
    transpose_split<1><<<gT, blk, 0, stream>>>(Wv, T_hi, T_lo);
    gemm_sk<1><<<gG, blk, 0, stream>>>(x_hi, x_lo, T_hi, T_lo, part);
    reduce_k<0><<<gR, blk, 0, stream>>>(part, bv, nullptr, nullptr, v_hi, v_lo, nullptr);

    // o = v @ Wo + bo
    transpose_split<1><<<gT, blk, 0, stream>>>(Wo, T_hi, T_lo);
    gemm_sk<1><<<gG, blk, 0, stream>>>(v_hi, v_lo, T_hi, T_lo, part);
    reduce_k<1><<<gR, blk, 0, stream>>>(part, bo, nullptr, nullptr, o_hi, o_lo, o_f32);

    // logits = (o @ mem^T) / (zn x mn)   [mem native rows ARE B^T layout]
    rownorm_kernel<<<MB, blk, 0, stream>>>(o_f32, zn, FF);
    gemm_sk<1><<<gG, blk, 0, stream>>>(o_hi, o_lo, M_hi, M_lo, part);
    reduce_k<2><<<gR, blk, 0, stream>>>(part, nullptr, zn, mn, nullptr, nullptr, logit);

    // softmax/shrink/renorm/entropy -> w (bf16)
    softmax_shrink_kernel<<<MB, blk, 0, stream>>>(logit, w_hi, rowe);

    // z_hat = w @ mem  (plain bf16; needs mem^T planes)
    transpose_split<0><<<gT, blk, 0, stream>>>(mem, T_hi, nullptr);
    gemm_sk<0><<<gG, blk, 0, stream>>>(w_hi, nullptr, T_hi, nullptr, part);
    reduce_k<3><<<gR, blk, 0, stream>>>(part, nullptr, nullptr, nullptr, nullptr, nullptr, out);

    loss_kernel<<<1, blk, 0, stream>>>(rowe, out + (size_t)MB * FF);
}